// Round 8
// baseline (614.836 us; speedup 1.0000x reference)
//
#include <hip/hip_runtime.h>
#include <stdint.h>

typedef __bf16 bf16;
typedef __bf16 bf16x8 __attribute__((ext_vector_type(8)));
typedef __bf16 bf16x4 __attribute__((ext_vector_type(4)));
typedef float  f32x4  __attribute__((ext_vector_type(4)));
typedef unsigned int u32;

#define E_DIM 1024
#define S_LEN 2048
#define BATCH 2
#define NH 16
#define DH 64

#define NEG_INF (-__builtin_inff())

union BU { u32 u[4]; bf16x8 h; };

__device__ __forceinline__ u32 cvtpk_bf16(float lo, float hi) {
    u32 r;
    asm("v_cvt_pk_bf16_f32 %0, %1, %2" : "=v"(r) : "v"(lo), "v"(hi));
    return r;
}
__device__ __forceinline__ void pswap32(u32 &a, u32 &b) {
    asm("v_permlane32_swap_b32 %0, %1" : "+v"(a), "+v"(b));
}
__device__ __forceinline__ void pswap16(u32 &a, u32 &b) {
    asm("v_permlane16_swap_b32 %0, %1" : "+v"(a), "+v"(b));
}
// raw v_exp_f32 (2^x); avoids ocml exp2f fixup code. exp(-inf)=0 as needed.
__device__ __forceinline__ float fast_exp2(float x) {
    float r;
    asm("v_exp_f32 %0, %1" : "=v"(r) : "v"(x));
    return r;
}

// async global->LDS, 16B per lane; LDS dst = wave-uniform base + lane*16 (m104)
__device__ __forceinline__ void load_lds16(const bf16* g, bf16* l) {
    __builtin_amdgcn_global_load_lds(
        (const __attribute__((address_space(1))) void*)g,
        (__attribute__((address_space(3))) void*)l, 16, 0, 0);
}

// ---------------------------------------------------------------------------
// fp32 -> bf16 conversion for x, Wq, Wk, Wv, Wo  (+ y==5: zero attn counters)
// ---------------------------------------------------------------------------
__global__ __launch_bounds__(256) void convert_kernel(
    const float* __restrict__ s0, const float* __restrict__ s1,
    const float* __restrict__ s2, const float* __restrict__ s3,
    const float* __restrict__ s4,
    bf16* __restrict__ d0, bf16* __restrict__ d1, bf16* __restrict__ d2,
    bf16* __restrict__ d3, bf16* __restrict__ d4,
    int* __restrict__ Cnt,
    int n0, int n1)
{
    if (blockIdx.y == 5) {
        if (blockIdx.x == 0) {          // zero 512 chunk-counters (32 bh x 16 qt)
            Cnt[threadIdx.x] = 0;
            Cnt[threadIdx.x + 256] = 0;
        }
        return;
    }
    const float* src; bf16* dst; int n;
    switch (blockIdx.y) {
        case 0:  src = s0; dst = d0; n = n0; break;
        case 1:  src = s1; dst = d1; n = n1; break;
        case 2:  src = s2; dst = d2; n = n1; break;
        case 3:  src = s3; dst = d3; n = n1; break;
        default: src = s4; dst = d4; n = n1; break;
    }
    int i = (blockIdx.x * 256 + threadIdx.x) * 4;
    if (i >= n) return;
    float4 v = *(const float4*)(src + i);
    bf16x4 o;
    o[0] = (bf16)v.x; o[1] = (bf16)v.y; o[2] = (bf16)v.z; o[3] = (bf16)v.w;
    *(bf16x4*)(dst + i) = o;
}

// ---------------------------------------------------------------------------
// GEMM: m97 width-16 async staging + single-barrier double buffer, BK=32,
// 128x128 tiles (R6 geometry — R7's 64x128 regressed: worse FLOP/LDS-byte).
// R8: T2 XOR-swizzle on As/Bs. Rows are 64B (BK=32 bf16): linear layout puts
// 16 lanes' ds_read_b128 on banks {0,16} = 8-way conflict (3.15M cy at R6).
// Swizzle (involution, rule 21): LDS[row][c] holds global[row][c ^ ((row>>1)&3)]
// via pre-swizzled GLOBAL source (LDS dest stays linear for global_load_lds);
// reads use chunk quad ^ ((l16>>1)&3) -> 2 lanes/bank-group = conflict-free.
// Per-XCD compact chunk decode keeps panels L2-local (R6: FETCH 36->20MB).
// ---------------------------------------------------------------------------
__global__ __launch_bounds__(256) void gemm_kernel(
    const bf16* __restrict__ A,
    const bf16* __restrict__ W,
    const float* __restrict__ bias0, const float* __restrict__ bias1,
    const float* __restrict__ bias2,
    bf16* __restrict__ outQ, bf16* __restrict__ outK, bf16* __restrict__ outVt,
    float* __restrict__ outF, int final_mode)
{
    __shared__ bf16 As[2][128 * 32];
    __shared__ bf16 Bs[2][128 * 32];

    // L2-locality decode: xcd = bid&7; per-XCD chunk of tiles.
    const int bid = blockIdx.x;
    const int xcd = bid & 7, idx = bid >> 3;
    int mtile, ntile;
    if (final_mode) {   // grid 256 = 32m x 8n; chunk 8m x 4n per XCD
        mtile = (xcd >> 1) * 8 + (idx >> 2);
        ntile = (xcd & 1) * 4 + (idx & 3);
    } else {            // grid 768 = 32m x 24n; chunk 8m x 12n per XCD
        mtile = (xcd >> 1) * 8 + idx / 12;
        ntile = (xcd & 1) * 12 + idx % 12;
    }
    const int bm = mtile * 128, bn = ntile * 128;
    const int mode = final_mode ? 3 : (bn >> 10);
    const float* bias = (mode == 1) ? bias1 : (mode == 2 ? bias2 : bias0);

    const int t = threadIdx.x;
    const int lane = t & 63, w = t >> 6;
    const int quad = lane >> 4, l16 = lane & 15;
    const int wm = (w & 1) * 64, wn = (w >> 1) * 64;

    // staging map: row = r0 + lane>>2; SWIZZLED global chunk (lane&3)^bits1-2(row)
    const int r0 = w * 16;
    const int srow = r0 + (lane >> 2);
    const int scol = ((lane & 3) ^ ((lane >> 3) & 3)) * 8;   // (row>>1)&3 == (lane>>3)&3
    const bf16* Ag0 = A + (size_t)(bm + srow) * E_DIM + scol;
    const bf16* Ag1 = Ag0 + (size_t)64 * E_DIM;
    const bf16* Wg0 = W + (size_t)(bn + srow) * E_DIM + scol;
    const bf16* Wg1 = Wg0 + (size_t)64 * E_DIM;

    f32x4 acc[4][4];
#pragma unroll
    for (int i = 0; i < 4; i++)
#pragma unroll
        for (int j = 0; j < 4; j++) acc[i][j] = f32x4{0.f, 0.f, 0.f, 0.f};

    load_lds16(Ag0, As[0] + r0 * 32);
    load_lds16(Ag1, As[0] + (64 + r0) * 32);
    load_lds16(Wg0, Bs[0] + r0 * 32);
    load_lds16(Wg1, Bs[0] + (64 + r0) * 32);

    // read-side swizzle: row bits 1-2 come from l16 (wm, i*16 are 16-multiples)
    const int rchunk = (quad ^ ((l16 >> 1) & 3)) * 8;

    int cur = 0;
    for (int kt = 0; kt < E_DIM; kt += 32) {
        __syncthreads();

        if (kt + 32 < E_DIM) {
            const int nxt = cur ^ 1;
            load_lds16(Ag0 + kt + 32, As[nxt] + r0 * 32);
            load_lds16(Ag1 + kt + 32, As[nxt] + (64 + r0) * 32);
            load_lds16(Wg0 + kt + 32, Bs[nxt] + r0 * 32);
            load_lds16(Wg1 + kt + 32, Bs[nxt] + (64 + r0) * 32);
        }

        bf16x8 af[4], bfr[4];
#pragma unroll
        for (int i = 0; i < 4; i++)
            af[i] = *(const bf16x8*)(As[cur] + (wm + i * 16 + l16) * 32 + rchunk);
#pragma unroll
        for (int j = 0; j < 4; j++)
            bfr[j] = *(const bf16x8*)(Bs[cur] + (wn + j * 16 + l16) * 32 + rchunk);
#pragma unroll
        for (int i = 0; i < 4; i++)
#pragma unroll
            for (int j = 0; j < 4; j++)
                acc[i][j] = __builtin_amdgcn_mfma_f32_16x16x32_bf16(af[i], bfr[j], acc[i][j], 0, 0, 0);

        cur ^= 1;
    }

#pragma unroll
    for (int j = 0; j < 4; j++) {
        const int n = bn + wn + j * 16 + l16;    // absolute col (0..3071 fused)
        const int nl = n & 1023;                 // col within the mode
        const float bv = bias[nl];
#pragma unroll
        for (int i = 0; i < 4; i++) {
            const int m0 = bm + wm + i * 16 + quad * 4;
            if (mode == 3) {
#pragma unroll
                for (int r = 0; r < 4; r++)
                    outF[(size_t)(m0 + r) * E_DIM + nl] = acc[i][j][r] + bv;
            } else if (mode == 2) {
                const int b_ = m0 >> 11, s0 = m0 & (S_LEN - 1);
                const int h = nl >> 6, d = nl & 63;
                bf16x4 pv;
#pragma unroll
                for (int r = 0; r < 4; r++) pv[r] = (bf16)(acc[i][j][r] + bv);
                *(bf16x4*)(outVt + ((size_t)((b_ * NH + h) * DH + d)) * S_LEN + s0) = pv;
            } else {
                bf16* o = (mode == 0) ? outQ : outK;
                // Q pre-scaled by 0.125 * log2(e) so attn softmax uses exp2
                const float sc = (mode == 0) ? 0.18033688f : 1.0f;
                const int h = nl >> 6, d = nl & 63;
#pragma unroll
                for (int r = 0; r < 4; r++) {
                    const int m = m0 + r;
                    const int b_ = m >> 11, s = m & (S_LEN - 1);
                    o[((size_t)(b_ * NH + h) * S_LEN + s) * DH + d] = (bf16)((acc[i][j][r] + bv) * sc);
                }
            }
        }
    }
}

// ---------------------------------------------------------------------------
// Flash attention, causal — balanced chunks with NON-ATOMIC partial stores
// (R3 structure) + R8: fused normalization via last-chunk-finisher. After a
// chunk stores its (O,l) partial slot: __threadfence (release), device-scope
// atomicAdd on Cnt[bh*16+qt]; the block that sees old==nc-1 acquires
// (__threadfence), sums the live slots, normalizes, writes bf16 Ab. Deletes
// the separate norm dispatch; reduction overlaps other blocks' compute.
// ---------------------------------------------------------------------------
__global__ __launch_bounds__(512, 4) void attn_kernel(
    const bf16* __restrict__ Qb, const bf16* __restrict__ Kb,
    const bf16* __restrict__ Vtb,
    float* __restrict__ Opart, float* __restrict__ Lpart,
    bf16* __restrict__ Ab, int* __restrict__ Cnt)
{
    __shared__ __align__(16) char smem[35840];
    __shared__ int sFlag;
    bf16* Ks = (bf16*)smem;              // [128][72]  18.0 KB
    bf16* Vs = (bf16*)(smem + 18432);    // [64][136]  17.0 KB

    const int t = threadIdx.x, lane = t & 63, w = t >> 6;
    const int quad = lane >> 4, l16 = lane & 15;
    const int qs = w & 3, kh = w >> 2;   // q-stripe 0..3, k-half 0..1

    // block -> (xcd, bh, chunk): i = [g(0..39)][bh_local(0..3)][xcd(0..7)]
    const int i = blockIdx.x;
    const int xcd = i & 7, idx = i >> 3;       // idx 0..159
    const int bh  = (xcd << 2) | (idx & 3);    // 4 bh per XCD (L2-resident K/V)
    const int g   = idx >> 2;                  // chunk id 0..39
    int qt, c0;
    if (g < 4)       { qt = g;                            c0 = 0; }
    else if (g < 12) { int u = g - 4;  qt = 4 + (u >> 1); c0 = u & 1; }
    else if (g < 24) { int u = g - 12; qt = 8 + u / 3;    c0 = u % 3; }
    else             { int u = g - 24; qt = 12 + (u >> 2); c0 = u & 3; }
    const int k0 = c0 * 4;                          // first k-tile of chunk
    const int k1 = (k0 + 3 < qt) ? k0 + 3 : qt;     // last k-tile (incl)

    const bf16* Qg = Qb + (size_t)bh * S_LEN * DH;
    const bf16* Kg = Kb + (size_t)bh * S_LEN * DH;
    const bf16* Vg = Vtb + (size_t)bh * DH * S_LEN;
    float* Op = Opart + ((size_t)(bh * 16 + qt) * 4 + c0) * (128 * 64);
    float* Lp = Lpart + ((size_t)(bh * 16 + qt) * 4 + c0) * 128;

    const int qrow0 = qt * 128 + qs * 32;

    // Q B-fragments: lane = q-row (l16) of each 16-q stripe, cols d
    bf16x8 qf[2][2];
#pragma unroll
    for (int qh = 0; qh < 2; qh++) {
        const bf16* qp = Qg + (size_t)(qrow0 + qh * 16 + l16) * DH + quad * 8;
        qf[qh][0] = *(const bf16x8*)(qp);
        qf[qh][1] = *(const bf16x8*)(qp + 32);
    }

    f32x4 o[2][4];          // O^T frags: lane=q(l16), regs d=dt*16+quad*4+r
    f32x4 lacc[2];          // partial row sums (this lane's k subset)
#pragma unroll
    for (int qh = 0; qh < 2; qh++) {
        lacc[qh] = f32x4{0.f, 0.f, 0.f, 0.f};
#pragma unroll
        for (int dt = 0; dt < 4; dt++) o[qh][dt] = f32x4{0.f, 0.f, 0.f, 0.f};
    }

    const int kr0 = t >> 3, kce = (t & 7) * 8;      // K staging map
    const int vr0 = t >> 4, vce = (t & 15) * 8;     // V staging map

    // prologue staging load (first tile of chunk)
    const int kb0 = k0 * 128;
    uint4 kA = *(const uint4*)(Kg + (size_t)(kb0 + kr0) * DH + kce);
    uint4 kB = *(const uint4*)(Kg + (size_t)(kb0 + kr0 + 64) * DH + kce);
    uint4 vA = *(const uint4*)(Vg + (size_t)vr0 * S_LEN + kb0 + vce);
    uint4 vB = *(const uint4*)(Vg + (size_t)(vr0 + 32) * S_LEN + kb0 + vce);

    for (int kt = k0; kt <= k1; kt++) {
        __syncthreads();            // previous tile's LDS reads done
        *(uint4*)(Ks + kr0 * 72 + kce) = kA;
        *(uint4*)(Ks + (kr0 + 64) * 72 + kce) = kB;
        *(uint4*)(Vs + vr0 * 136 + vce) = vA;
        *(uint4*)(Vs + (vr0 + 32) * 136 + vce) = vB;
        __syncthreads();            // staged tile visible

        if (kt < k1) {              // T14: issue next tile's loads under compute
            const int kb = (kt + 1) * 128;
            kA = *(const uint4*)(Kg + (size_t)(kb + kr0) * DH + kce);
            kB = *(const uint4*)(Kg + (size_t)(kb + kr0 + 64) * DH + kce);
            vA = *(const uint4*)(Vg + (size_t)vr0 * S_LEN + kb + vce);
            vB = *(const uint4*)(Vg + (size_t)(vr0 + 32) * S_LEN + kb + vce);
        }

        const bool diag = (kt == qt);

#pragma unroll
        for (int itp = 0; itp < 2; itp++) {
            // ---- S^T = mfma(K, Q): lane holds S[q=l16][k=itg*16+quad*4+r]
            f32x4 p[2][2];
#pragma unroll
            for (int e = 0; e < 2; e++) {
                const int itg = kh * 4 + itp * 2 + e;
                const bf16* kp = Ks + (itg * 16 + l16) * 72 + quad * 8;
                bf16x8 kf0 = *(const bf16x8*)(kp);
                bf16x8 kf1 = *(const bf16x8*)(kp + 32);
#pragma unroll
                for (int qh = 0; qh < 2; qh++) {
                    f32x4 s = __builtin_amdgcn_mfma_f32_16x16x32_bf16(
                        kf0, qf[qh][0], f32x4{0.f, 0.f, 0.f, 0.f}, 0, 0, 0);
                    s = __builtin_amdgcn_mfma_f32_16x16x32_bf16(
                        kf1, qf[qh][1], s, 0, 0, 0);
                    if (diag) {
                        const int kloc = kh * 64 + (itp * 2 + e) * 16 + quad * 4;
                        const int qloc = qs * 32 + qh * 16 + l16;
#pragma unroll
                        for (int r = 0; r < 4; r++)
                            if (kloc + r > qloc) s[r] = NEG_INF;
                    }
                    f32x4 pe;
#pragma unroll
                    for (int r = 0; r < 4; r++) pe[r] = fast_exp2(s[r]);
                    lacc[qh] += pe;
                    p[qh][e] = pe;
                }
            }

            // ---- P -> B-frag: cvt_pk pairs, then swap32+swap16 places
            // k = quad*8 + {0..7} at each quad (in-register transpose)
            BU bu0, bu1;
            {
                u32 a0 = cvtpk_bf16(p[0][0][0], p[0][0][1]);
                u32 a1 = cvtpk_bf16(p[0][0][2], p[0][0][3]);
                u32 b0 = cvtpk_bf16(p[0][1][0], p[0][1][1]);
                u32 b1 = cvtpk_bf16(p[0][1][2], p[0][1][3]);
                pswap32(a0, b0); pswap16(a0, b0);
                pswap32(a1, b1); pswap16(a1, b1);
                bu0.u[0] = a0; bu0.u[1] = a1; bu0.u[2] = b0; bu0.u[3] = b1;
            }
            {
                u32 a0 = cvtpk_bf16(p[1][0][0], p[1][0][1]);
                u32 a1 = cvtpk_bf16(p[1][0][2], p[1][0][3]);
                u32 b0 = cvtpk_bf16(p[1][1][0], p[1][1][1]);
                u32 b1 = cvtpk_bf16(p[1][1][2], p[1][1][3]);
                pswap32(a0, b0); pswap16(a0, b0);
                pswap32(a1, b1); pswap16(a1, b1);
                bu1.u[0] = a0; bu1.u[1] = a1; bu1.u[2] = b0; bu1.u[3] = b1;
            }

            // ---- O^T += mfma(V^T-frag, P-frag)
            const int ksg = kh * 2 + itp;
#pragma unroll
            for (int dt = 0; dt < 4; dt++) {
                bf16x8 vf = *(const bf16x8*)(Vs + (dt * 16 + l16) * 136 + ksg * 32 + quad * 8);
                o[0][dt] = __builtin_amdgcn_mfma_f32_16x16x32_bf16(vf, bu0.h, o[0][dt], 0, 0, 0);
                o[1][dt] = __builtin_amdgcn_mfma_f32_16x16x32_bf16(vf, bu1.h, o[1][dt], 0, 0, 0);
            }
        }
    }

    // ---- epilogue: quad-reduce l, cross-k-half combine via LDS, then
    // coalesced f32x4 partial stores into this chunk's own slot.
    float lsum[2];
#pragma unroll
    for (int qh = 0; qh < 2; qh++) {
        float l = lacc[qh][0] + lacc[qh][1] + lacc[qh][2] + lacc[qh][3];
        l += __shfl_xor(l, 16);
        l += __shfl_xor(l, 32);
        lsum[qh] = l;
    }

    __syncthreads();                         // all LDS reads done; reuse smem
    f32x4* Or = (f32x4*)smem;                // 2048 x 16B = 32 KB
    float*  Lr = (float*)(smem + 32768);     // 128 x 4B

    if (kh == 1) {
#pragma unroll
        for (int qh = 0; qh < 2; qh++) {
#pragma unroll
            for (int dt = 0; dt < 4; dt++)
                Or[(((qs * 2 + qh) * 4 + dt) * 4 + quad) * 16 + l16] = o[qh][dt];
            if (quad == 0) Lr[(qs * 2 + qh) * 16 + l16] = lsum[qh];
        }
    }
    __syncthreads();
    if (kh == 0) {
#pragma unroll
        for (int qh = 0; qh < 2; qh++) {
            const float lc = lsum[qh] + Lr[(qs * 2 + qh) * 16 + l16];
            const int row = qs * 32 + qh * 16 + l16;
            if (quad == 0) Lp[row] = lc;
#pragma unroll
            for (int dt = 0; dt < 4; dt++) {
                f32x4 ov = o[qh][dt] + Or[(((qs * 2 + qh) * 4 + dt) * 4 + quad) * 16 + l16];
                *(f32x4*)(Op + (size_t)row * 64 + dt * 16 + quad * 4) = ov;
            }
        }
    }

    // ---- fused normalization: last chunk of (bh,qt) reduces + writes Ab
    __threadfence();                         // release partial stores (device)
    __syncthreads();
    if (t == 0) sFlag = atomicAdd(&Cnt[bh * 16 + qt], 1);
    __syncthreads();
    const int nc = (qt >> 2) + 1;            // live slots for this q-tile
    if (sFlag == nc - 1) {
        __threadfence();                     // acquire other chunks' stores
        const float* Ob = Opart + ((size_t)(bh * 16 + qt) * 4) * (128 * 64);
        const float* Lb = Lpart + ((size_t)(bh * 16 + qt) * 4) * 128;
        bf16* Aq = Ab + ((size_t)(bh >> 4) * S_LEN + (size_t)qt * 128) * E_DIM
                      + (bh & 15) * DH;
        for (int task = t; task < 2048; task += 512) {   // 128 rows x 16 chunks
            const int row = task >> 4, dc = (task & 15) * 4;
            float l = Lb[row];
            f32x4 ov = *(const f32x4*)(Ob + (size_t)row * 64 + dc);
            for (int c = 1; c < nc; c++) {
                l += Lb[c * 128 + row];
                ov += *(const f32x4*)(Ob + (size_t)c * (128 * 64) + (size_t)row * 64 + dc);
            }
            const float inv = 1.0f / l;
            bf16x4 w4;
#pragma unroll
            for (int r = 0; r < 4; r++) w4[r] = (bf16)(ov[r] * inv);
            *(bf16x4*)(Aq + (size_t)row * E_DIM + dc) = w4;
        }
    }
}

// ---------------------------------------------------------------------------
extern "C" void kernel_launch(void* const* d_in, const int* in_sizes, int n_in,
                              void* d_out, int out_size, void* d_ws, size_t ws_size,
                              hipStream_t stream)
{
    const float* x  = (const float*)d_in[0];
    const float* Wq = (const float*)d_in[1];
    const float* bq = (const float*)d_in[2];
    const float* Wk = (const float*)d_in[3];
    const float* bk = (const float*)d_in[4];
    const float* Wv = (const float*)d_in[5];
    const float* bv = (const float*)d_in[6];
    const float* Wo = (const float*)d_in[7];
    const float* bo = (const float*)d_in[8];
    float* out = (float*)d_out;

    char* ws = (char*)d_ws;
    const size_t MB = 1ull << 20;
    bf16*  xb    = (bf16*)(ws + 0);        //  8 MB: x bf16 [4096][1024]
    bf16*  wqb   = (bf16*)(ws + 8 * MB);   //  2 MB (wqb/wkb/wvb contiguous = [3072][1024])
    bf16*  wkb   = (bf16*)(ws + 10 * MB);  //  2 MB
    bf16*  wvb   = (bf16*)(ws + 12 * MB);  //  2 MB
    bf16*  wob   = (bf16*)(ws + 14 * MB);  //  2 MB
    bf16*  Qb    = (bf16*)(ws + 16 * MB);  //  8 MB: [b][h][s][d] (scaled 0.125*log2e)
    bf16*  Kb    = (bf16*)(ws + 24 * MB);  //  8 MB: [b][h][s][d]
    bf16*  Vtb   = (bf16*)(ws + 32 * MB);  //  8 MB: [b][h][d][s]
    bf16*  Ab    = (bf16*)(ws + 40 * MB);  //  8 MB: attn out [b][s][e]
    float* Opart = (float*)(ws + 48 * MB); // 64 MB: f32 [bh][qt][4][128][64]
    float* Lpart = (float*)(ws + 112 * MB);//  1 MB: f32 [bh][qt][4][128]
    int*   Cnt   = (int*)(ws + 113 * MB);  //  2 KB: [32][16] chunk counters

    // 1) fp32 -> bf16 for x and weights; zero attn chunk counters (y==5)
    convert_kernel<<<dim3(4096, 6), 256, 0, stream>>>(
        x, Wq, Wk, Wv, Wo, xb, wqb, wkb, wvb, wob, Cnt, 4194304, 1048576);

    // 2) fused Q/K/V projection: one dispatch, W = [3072][1024] contiguous
    gemm_kernel<<<dim3(768), 256, 0, stream>>>(
        xb, wqb, bq, bk, bv, Qb, Kb, Vtb, nullptr, 0);

    // 3) causal flash attention + fused last-chunk normalization -> Ab
    attn_kernel<<<dim3(1280), 512, 0, stream>>>(
        Qb, Kb, Vtb, Opart, Lpart, Ab, Cnt);

    // 4) output projection -> fp32 d_out
    gemm_kernel<<<dim3(256), 256, 0, stream>>>(
        Ab, wob, bo, bo, bo, nullptr, nullptr, nullptr, out, 1);
}

// Round 10
// 201.742 us; speedup vs baseline: 3.0476x; 3.0476x over previous
//
#include <hip/hip_runtime.h>
#include <stdint.h>

typedef __bf16 bf16;
typedef __bf16 bf16x8 __attribute__((ext_vector_type(8)));
typedef __bf16 bf16x4 __attribute__((ext_vector_type(4)));
typedef float  f32x4  __attribute__((ext_vector_type(4)));
typedef unsigned int u32;

#define E_DIM 1024
#define S_LEN 2048
#define BATCH 2
#define NH 16
#define DH 64

#define NEG_INF (-__builtin_inff())

union BU { u32 u[4]; bf16x8 h; };

__device__ __forceinline__ u32 cvtpk_bf16(float lo, float hi) {
    u32 r;
    asm("v_cvt_pk_bf16_f32 %0, %1, %2" : "=v"(r) : "v"(lo), "v"(hi));
    return r;
}
__device__ __forceinline__ void pswap32(u32 &a, u32 &b) {
    asm("v_permlane32_swap_b32 %0, %1" : "+v"(a), "+v"(b));
}
__device__ __forceinline__ void pswap16(u32 &a, u32 &b) {
    asm("v_permlane16_swap_b32 %0, %1" : "+v"(a), "+v"(b));
}
// raw v_exp_f32 (2^x); avoids ocml exp2f fixup code. exp(-inf)=0 as needed.
__device__ __forceinline__ float fast_exp2(float x) {
    float r;
    asm("v_exp_f32 %0, %1" : "=v"(r) : "v"(x));
    return r;
}

// async global->LDS, 16B per lane; LDS dst = wave-uniform base + lane*16 (m104)
__device__ __forceinline__ void load_lds16(const bf16* g, bf16* l) {
    __builtin_amdgcn_global_load_lds(
        (const __attribute__((address_space(1))) void*)g,
        (__attribute__((address_space(3))) void*)l, 16, 0, 0);
}

// ---------------------------------------------------------------------------
// fp32 -> bf16 conversion for x, Wq, Wk, Wv, Wo
// ---------------------------------------------------------------------------
__global__ __launch_bounds__(256) void convert_kernel(
    const float* __restrict__ s0, const float* __restrict__ s1,
    const float* __restrict__ s2, const float* __restrict__ s3,
    const float* __restrict__ s4,
    bf16* __restrict__ d0, bf16* __restrict__ d1, bf16* __restrict__ d2,
    bf16* __restrict__ d3, bf16* __restrict__ d4,
    int n0, int n1)
{
    const float* src; bf16* dst; int n;
    switch (blockIdx.y) {
        case 0:  src = s0; dst = d0; n = n0; break;
        case 1:  src = s1; dst = d1; n = n1; break;
        case 2:  src = s2; dst = d2; n = n1; break;
        case 3:  src = s3; dst = d3; n = n1; break;
        default: src = s4; dst = d4; n = n1; break;
    }
    int i = (blockIdx.x * 256 + threadIdx.x) * 4;
    if (i >= n) return;
    float4 v = *(const float4*)(src + i);
    bf16x4 o;
    o[0] = (bf16)v.x; o[1] = (bf16)v.y; o[2] = (bf16)v.z; o[3] = (bf16)v.w;
    *(bf16x4*)(dst + i) = o;
}

// ---------------------------------------------------------------------------
// GEMM: m97 width-16 async staging + single-barrier double buffer, BK=32,
// 128x128 tiles. R8-kept: T2 XOR-swizzle on As/Bs (rows are 64B; linear
// layout = 8-way ds_read conflict, 3.15M cy at R6). Involution (rule 21):
// LDS[row][c] holds global[row][c ^ ((row>>1)&3)] via pre-swizzled GLOBAL
// source (LDS dest stays linear for global_load_lds); reads use chunk
// quad ^ ((l16>>1)&3). Per-XCD compact chunk decode keeps panels L2-local.
// R9: reverted R8's fused-norm fence experiment (device-scope threadfence
// forces per-XCD L2 writeback/invalidate -> 10x attn regression).
// ---------------------------------------------------------------------------
__global__ __launch_bounds__(256) void gemm_kernel(
    const bf16* __restrict__ A,
    const bf16* __restrict__ W,
    const float* __restrict__ bias0, const float* __restrict__ bias1,
    const float* __restrict__ bias2,
    bf16* __restrict__ outQ, bf16* __restrict__ outK, bf16* __restrict__ outVt,
    float* __restrict__ outF, int final_mode)
{
    __shared__ bf16 As[2][128 * 32];
    __shared__ bf16 Bs[2][128 * 32];

    // L2-locality decode: xcd = bid&7; per-XCD chunk of tiles.
    const int bid = blockIdx.x;
    const int xcd = bid & 7, idx = bid >> 3;
    int mtile, ntile;
    if (final_mode) {   // grid 256 = 32m x 8n; chunk 8m x 4n per XCD
        mtile = (xcd >> 1) * 8 + (idx >> 2);
        ntile = (xcd & 1) * 4 + (idx & 3);
    } else {            // grid 768 = 32m x 24n; chunk 8m x 12n per XCD
        mtile = (xcd >> 1) * 8 + idx / 12;
        ntile = (xcd & 1) * 12 + idx % 12;
    }
    const int bm = mtile * 128, bn = ntile * 128;
    const int mode = final_mode ? 3 : (bn >> 10);
    const float* bias = (mode == 1) ? bias1 : (mode == 2 ? bias2 : bias0);

    const int t = threadIdx.x;
    const int lane = t & 63, w = t >> 6;
    const int quad = lane >> 4, l16 = lane & 15;
    const int wm = (w & 1) * 64, wn = (w >> 1) * 64;

    // staging map: row = r0 + lane>>2; SWIZZLED global chunk (lane&3)^bits1-2(row)
    const int r0 = w * 16;
    const int srow = r0 + (lane >> 2);
    const int scol = ((lane & 3) ^ ((lane >> 3) & 3)) * 8;   // (row>>1)&3 == (lane>>3)&3
    const bf16* Ag0 = A + (size_t)(bm + srow) * E_DIM + scol;
    const bf16* Ag1 = Ag0 + (size_t)64 * E_DIM;
    const bf16* Wg0 = W + (size_t)(bn + srow) * E_DIM + scol;
    const bf16* Wg1 = Wg0 + (size_t)64 * E_DIM;

    f32x4 acc[4][4];
#pragma unroll
    for (int i = 0; i < 4; i++)
#pragma unroll
        for (int j = 0; j < 4; j++) acc[i][j] = f32x4{0.f, 0.f, 0.f, 0.f};

    load_lds16(Ag0, As[0] + r0 * 32);
    load_lds16(Ag1, As[0] + (64 + r0) * 32);
    load_lds16(Wg0, Bs[0] + r0 * 32);
    load_lds16(Wg1, Bs[0] + (64 + r0) * 32);

    // read-side swizzle: row bits 1-2 come from l16 (wm, i*16 are 16-multiples)
    const int rchunk = (quad ^ ((l16 >> 1) & 3)) * 8;

    int cur = 0;
    for (int kt = 0; kt < E_DIM; kt += 32) {
        __syncthreads();

        if (kt + 32 < E_DIM) {
            const int nxt = cur ^ 1;
            load_lds16(Ag0 + kt + 32, As[nxt] + r0 * 32);
            load_lds16(Ag1 + kt + 32, As[nxt] + (64 + r0) * 32);
            load_lds16(Wg0 + kt + 32, Bs[nxt] + r0 * 32);
            load_lds16(Wg1 + kt + 32, Bs[nxt] + (64 + r0) * 32);
        }

        bf16x8 af[4], bfr[4];
#pragma unroll
        for (int i = 0; i < 4; i++)
            af[i] = *(const bf16x8*)(As[cur] + (wm + i * 16 + l16) * 32 + rchunk);
#pragma unroll
        for (int j = 0; j < 4; j++)
            bfr[j] = *(const bf16x8*)(Bs[cur] + (wn + j * 16 + l16) * 32 + rchunk);
#pragma unroll
        for (int i = 0; i < 4; i++)
#pragma unroll
            for (int j = 0; j < 4; j++)
                acc[i][j] = __builtin_amdgcn_mfma_f32_16x16x32_bf16(af[i], bfr[j], acc[i][j], 0, 0, 0);

        cur ^= 1;
    }

#pragma unroll
    for (int j = 0; j < 4; j++) {
        const int n = bn + wn + j * 16 + l16;    // absolute col (0..3071 fused)
        const int nl = n & 1023;                 // col within the mode
        const float bv = bias[nl];
#pragma unroll
        for (int i = 0; i < 4; i++) {
            const int m0 = bm + wm + i * 16 + quad * 4;
            if (mode == 3) {
#pragma unroll
                for (int r = 0; r < 4; r++)
                    outF[(size_t)(m0 + r) * E_DIM + nl] = acc[i][j][r] + bv;
            } else if (mode == 2) {
                const int b_ = m0 >> 11, s0 = m0 & (S_LEN - 1);
                const int h = nl >> 6, d = nl & 63;
                bf16x4 pv;
#pragma unroll
                for (int r = 0; r < 4; r++) pv[r] = (bf16)(acc[i][j][r] + bv);
                *(bf16x4*)(outVt + ((size_t)((b_ * NH + h) * DH + d)) * S_LEN + s0) = pv;
            } else {
                bf16* o = (mode == 0) ? outQ : outK;
                // Q pre-scaled by 0.125 * log2(e) so attn softmax uses exp2
                const float sc = (mode == 0) ? 0.18033688f : 1.0f;
                const int h = nl >> 6, d = nl & 63;
#pragma unroll
                for (int r = 0; r < 4; r++) {
                    const int m = m0 + r;
                    const int b_ = m >> 11, s = m & (S_LEN - 1);
                    o[((size_t)(b_ * NH + h) * S_LEN + s) * DH + d] = (bf16)((acc[i][j][r] + bv) * sc);
                }
            }
        }
    }
}

// ---------------------------------------------------------------------------
// Flash attention, causal — balanced chunks with NON-ATOMIC partial stores.
// (R3/R6 structure, verified at 202.5us total; R8's fused-norm reverted)
// ---------------------------------------------------------------------------
__global__ __launch_bounds__(512, 4) void attn_kernel(
    const bf16* __restrict__ Qb, const bf16* __restrict__ Kb,
    const bf16* __restrict__ Vtb,
    float* __restrict__ Opart, float* __restrict__ Lpart)
{
    __shared__ __align__(16) char smem[35840];
    bf16* Ks = (bf16*)smem;              // [128][72]  18.0 KB
    bf16* Vs = (bf16*)(smem + 18432);    // [64][136]  17.0 KB

    const int t = threadIdx.x, lane = t & 63, w = t >> 6;
    const int quad = lane >> 4, l16 = lane & 15;
    const int qs = w & 3, kh = w >> 2;   // q-stripe 0..3, k-half 0..1

    // block -> (xcd, bh, chunk): i = [g(0..39)][bh_local(0..3)][xcd(0..7)]
    const int i = blockIdx.x;
    const int xcd = i & 7, idx = i >> 3;       // idx 0..159
    const int bh  = (xcd << 2) | (idx & 3);    // 4 bh per XCD (L2-resident K/V)
    const int g   = idx >> 2;                  // chunk id 0..39
    int qt, c0;
    if (g < 4)       { qt = g;                            c0 = 0; }
    else if (g < 12) { int u = g - 4;  qt = 4 + (u >> 1); c0 = u & 1; }
    else if (g < 24) { int u = g - 12; qt = 8 + u / 3;    c0 = u % 3; }
    else             { int u = g - 24; qt = 12 + (u >> 2); c0 = u & 3; }
    const int k0 = c0 * 4;                          // first k-tile of chunk
    const int k1 = (k0 + 3 < qt) ? k0 + 3 : qt;     // last k-tile (incl)

    const bf16* Qg = Qb + (size_t)bh * S_LEN * DH;
    const bf16* Kg = Kb + (size_t)bh * S_LEN * DH;
    const bf16* Vg = Vtb + (size_t)bh * DH * S_LEN;
    float* Op = Opart + ((size_t)(bh * 16 + qt) * 4 + c0) * (128 * 64);
    float* Lp = Lpart + ((size_t)(bh * 16 + qt) * 4 + c0) * 128;

    const int qrow0 = qt * 128 + qs * 32;

    // Q B-fragments: lane = q-row (l16) of each 16-q stripe, cols d
    bf16x8 qf[2][2];
#pragma unroll
    for (int qh = 0; qh < 2; qh++) {
        const bf16* qp = Qg + (size_t)(qrow0 + qh * 16 + l16) * DH + quad * 8;
        qf[qh][0] = *(const bf16x8*)(qp);
        qf[qh][1] = *(const bf16x8*)(qp + 32);
    }

    f32x4 o[2][4];          // O^T frags: lane=q(l16), regs d=dt*16+quad*4+r
    f32x4 lacc[2];          // partial row sums (this lane's k subset)
#pragma unroll
    for (int qh = 0; qh < 2; qh++) {
        lacc[qh] = f32x4{0.f, 0.f, 0.f, 0.f};
#pragma unroll
        for (int dt = 0; dt < 4; dt++) o[qh][dt] = f32x4{0.f, 0.f, 0.f, 0.f};
    }

    const int kr0 = t >> 3, kce = (t & 7) * 8;      // K staging map
    const int vr0 = t >> 4, vce = (t & 15) * 8;     // V staging map

    // prologue staging load (first tile of chunk)
    const int kb0 = k0 * 128;
    uint4 kA = *(const uint4*)(Kg + (size_t)(kb0 + kr0) * DH + kce);
    uint4 kB = *(const uint4*)(Kg + (size_t)(kb0 + kr0 + 64) * DH + kce);
    uint4 vA = *(const uint4*)(Vg + (size_t)vr0 * S_LEN + kb0 + vce);
    uint4 vB = *(const uint4*)(Vg + (size_t)(vr0 + 32) * S_LEN + kb0 + vce);

    for (int kt = k0; kt <= k1; kt++) {
        __syncthreads();            // previous tile's LDS reads done
        *(uint4*)(Ks + kr0 * 72 + kce) = kA;
        *(uint4*)(Ks + (kr0 + 64) * 72 + kce) = kB;
        *(uint4*)(Vs + vr0 * 136 + vce) = vA;
        *(uint4*)(Vs + (vr0 + 32) * 136 + vce) = vB;
        __syncthreads();            // staged tile visible

        if (kt < k1) {              // T14: issue next tile's loads under compute
            const int kb = (kt + 1) * 128;
            kA = *(const uint4*)(Kg + (size_t)(kb + kr0) * DH + kce);
            kB = *(const uint4*)(Kg + (size_t)(kb + kr0 + 64) * DH + kce);
            vA = *(const uint4*)(Vg + (size_t)vr0 * S_LEN + kb + vce);
            vB = *(const uint4*)(Vg + (size_t)(vr0 + 32) * S_LEN + kb + vce);
        }

        const bool diag = (kt == qt);

#pragma unroll
        for (int itp = 0; itp < 2; itp++) {
            // ---- S^T = mfma(K, Q): lane holds S[q=l16][k=itg*16+quad*4+r]
            f32x4 p[2][2];
#pragma unroll
            for (int e = 0; e < 2; e++) {
                const int itg = kh * 4 + itp * 2 + e;
                const bf16* kp = Ks + (itg * 16 + l16) * 72 + quad * 8;
                bf16x8 kf0 = *(const bf16x8*)(kp);
                bf16x8 kf1 = *(const bf16x8*)(kp + 32);
#pragma unroll
                for (int qh = 0; qh < 2; qh++) {
                    f32x4 s = __builtin_amdgcn_mfma_f32_16x16x32_bf16(
                        kf0, qf[qh][0], f32x4{0.f, 0.f, 0.f, 0.f}, 0, 0, 0);
                    s = __builtin_amdgcn_mfma_f32_16x16x32_bf16(
                        kf1, qf[qh][1], s, 0, 0, 0);
                    if (diag) {
                        const int kloc = kh * 64 + (itp * 2 + e) * 16 + quad * 4;
                        const int qloc = qs * 32 + qh * 16 + l16;
#pragma unroll
                        for (int r = 0; r < 4; r++)
                            if (kloc + r > qloc) s[r] = NEG_INF;
                    }
                    f32x4 pe;
#pragma unroll
                    for (int r = 0; r < 4; r++) pe[r] = fast_exp2(s[r]);
                    lacc[qh] += pe;
                    p[qh][e] = pe;
                }
            }

            // ---- P -> B-frag: cvt_pk pairs, then swap32+swap16 places
            // k = quad*8 + {0..7} at each quad (in-register transpose)
            BU bu0, bu1;
            {
                u32 a0 = cvtpk_bf16(p[0][0][0], p[0][0][1]);
                u32 a1 = cvtpk_bf16(p[0][0][2], p[0][0][3]);
                u32 b0 = cvtpk_bf16(p[0][1][0], p[0][1][1]);
                u32 b1 = cvtpk_bf16(p[0][1][2], p[0][1][3]);
                pswap32(a0, b0); pswap16(a0, b0);
                pswap32(a1, b1); pswap16(a1, b1);
                bu0.u[0] = a0; bu0.u[1] = a1; bu0.u[2] = b0; bu0.u[3] = b1;
            }
            {
                u32 a0 = cvtpk_bf16(p[1][0][0], p[1][0][1]);
                u32 a1 = cvtpk_bf16(p[1][0][2], p[1][0][3]);
                u32 b0 = cvtpk_bf16(p[1][1][0], p[1][1][1]);
                u32 b1 = cvtpk_bf16(p[1][1][2], p[1][1][3]);
                pswap32(a0, b0); pswap16(a0, b0);
                pswap32(a1, b1); pswap16(a1, b1);
                bu1.u[0] = a0; bu1.u[1] = a1; bu1.u[2] = b0; bu1.u[3] = b1;
            }

            // ---- O^T += mfma(V^T-frag, P-frag)
            const int ksg = kh * 2 + itp;
#pragma unroll
            for (int dt = 0; dt < 4; dt++) {
                bf16x8 vf = *(const bf16x8*)(Vs + (dt * 16 + l16) * 136 + ksg * 32 + quad * 8);
                o[0][dt] = __builtin_amdgcn_mfma_f32_16x16x32_bf16(vf, bu0.h, o[0][dt], 0, 0, 0);
                o[1][dt] = __builtin_amdgcn_mfma_f32_16x16x32_bf16(vf, bu1.h, o[1][dt], 0, 0, 0);
            }
        }
    }

    // ---- epilogue: quad-reduce l, cross-k-half combine via LDS, then
    // coalesced f32x4 partial stores into this chunk's own slot.
    float lsum[2];
#pragma unroll
    for (int qh = 0; qh < 2; qh++) {
        float l = lacc[qh][0] + lacc[qh][1] + lacc[qh][2] + lacc[qh][3];
        l += __shfl_xor(l, 16);
        l += __shfl_xor(l, 32);
        lsum[qh] = l;
    }

    __syncthreads();                         // all LDS reads done; reuse smem
    f32x4* Or = (f32x4*)smem;                // 2048 x 16B = 32 KB
    float*  Lr = (float*)(smem + 32768);     // 128 x 4B

    if (kh == 1) {
#pragma unroll
        for (int qh = 0; qh < 2; qh++) {
#pragma unroll
            for (int dt = 0; dt < 4; dt++)
                Or[(((qs * 2 + qh) * 4 + dt) * 4 + quad) * 16 + l16] = o[qh][dt];
            if (quad == 0) Lr[(qs * 2 + qh) * 16 + l16] = lsum[qh];
        }
    }
    __syncthreads();
    if (kh == 0) {
#pragma unroll
        for (int qh = 0; qh < 2; qh++) {
            const float lc = lsum[qh] + Lr[(qs * 2 + qh) * 16 + l16];
            const int row = qs * 32 + qh * 16 + l16;
            if (quad == 0) Lp[row] = lc;
#pragma unroll
            for (int dt = 0; dt < 4; dt++) {
                f32x4 ov = o[qh][dt] + Or[(((qs * 2 + qh) * 4 + dt) * 4 + quad) * 16 + l16];
                *(f32x4*)(Op + (size_t)row * 64 + dt * 16 + quad * 4) = ov;
            }
        }
    }
}

// ---------------------------------------------------------------------------
// normalize: sum the live partial slots, divide, write bf16 Ab[b][s][h*64+d]
// ---------------------------------------------------------------------------
__global__ __launch_bounds__(256) void norm_kernel(
    const float* __restrict__ Opart, const float* __restrict__ Lpart,
    bf16* __restrict__ Ab)
{
    const int j = (blockIdx.x * 256 + threadIdx.x) * 4;   // 4,194,304 total
    const int b = j >> 21, s = (j >> 10) & (S_LEN - 1), e = j & 1023;
    const int h = e >> 6, d = e & 63;
    const int bh = b * NH + h;
    const int qt = s >> 7, row = s & 127;
    const int nc = (qt >> 2) + 1;                 // live slots for this q-tile
    const float* Op = Opart + ((size_t)(bh * 16 + qt) * 4) * (128 * 64)
                    + (size_t)row * 64 + d;
    const float* Lp = Lpart + ((size_t)(bh * 16 + qt) * 4) * 128 + row;
    f32x4 ov = *(const f32x4*)Op;
    float l = Lp[0];
    for (int c = 1; c < nc; c++) {
        ov += *(const f32x4*)(Op + c * (128 * 64));
        l += Lp[c * 128];
    }
    const float inv = 1.0f / l;
    bf16x4 w4;
#pragma unroll
    for (int r = 0; r < 4; r++) w4[r] = (bf16)(ov[r] * inv);
    *(bf16x4*)(Ab + j) = w4;
}

// ---------------------------------------------------------------------------
extern "C" void kernel_launch(void* const* d_in, const int* in_sizes, int n_in,
                              void* d_out, int out_size, void* d_ws, size_t ws_size,
                              hipStream_t stream)
{
    const float* x  = (const float*)d_in[0];
    const float* Wq = (const float*)d_in[1];
    const float* bq = (const float*)d_in[2];
    const float* Wk = (const float*)d_in[3];
    const float* bk = (const float*)d_in[4];
    const float* Wv = (const float*)d_in[5];
    const float* bv = (const float*)d_in[6];
    const float* Wo = (const float*)d_in[7];
    const float* bo = (const float*)d_in[8];
    float* out = (float*)d_out;

    char* ws = (char*)d_ws;
    const size_t MB = 1ull << 20;
    bf16*  xb    = (bf16*)(ws + 0);        //  8 MB: x bf16 [4096][1024]
    bf16*  wqb   = (bf16*)(ws + 8 * MB);   //  2 MB (wqb/wkb/wvb contiguous = [3072][1024])
    bf16*  wkb   = (bf16*)(ws + 10 * MB);  //  2 MB
    bf16*  wvb   = (bf16*)(ws + 12 * MB);  //  2 MB
    bf16*  wob   = (bf16*)(ws + 14 * MB);  //  2 MB
    bf16*  Qb    = (bf16*)(ws + 16 * MB);  //  8 MB: [b][h][s][d] (scaled 0.125*log2e)
    bf16*  Kb    = (bf16*)(ws + 24 * MB);  //  8 MB: [b][h][s][d]
    bf16*  Vtb   = (bf16*)(ws + 32 * MB);  //  8 MB: [b][h][d][s]
    bf16*  Ab    = (bf16*)(ws + 40 * MB);  //  8 MB: attn out [b][s][e]
    float* Opart = (float*)(ws + 48 * MB); // 64 MB: f32 [bh][qt][4][128][64]
    float* Lpart = (float*)(ws + 112 * MB);//  1 MB: f32 [bh][qt][4][128]

    // 1) fp32 -> bf16 for x and the four weight matrices
    convert_kernel<<<dim3(4096, 5), 256, 0, stream>>>(
        x, Wq, Wk, Wv, Wo, xb, wqb, wkb, wvb, wob, 4194304, 1048576);

    // 2) fused Q/K/V projection: one dispatch, W = [3072][1024] contiguous
    gemm_kernel<<<dim3(768), 256, 0, stream>>>(
        xb, wqb, bq, bk, bv, Qb, Kb, Vtb, nullptr, 0);

    // 3) causal flash attention, balanced chunks -> per-chunk partial slots
    attn_kernel<<<dim3(1280), 512, 0, stream>>>(Qb, Kb, Vtb, Opart, Lpart);

    // 4) reduce partial slots + normalize -> bf16 Ab
    norm_kernel<<<dim3(4096), 256, 0, stream>>>(Opart, Lpart, Ab);

    // 5) output projection -> fp32 d_out
    gemm_kernel<<<dim3(256), 256, 0, stream>>>(
        Ab, wob, bo, bo, bo, nullptr, nullptr, nullptr, out, 1);
}

// Round 11
// 196.034 us; speedup vs baseline: 3.1364x; 1.0291x over previous
//
#include <hip/hip_runtime.h>
#include <stdint.h>

typedef __bf16 bf16;
typedef __bf16 bf16x8 __attribute__((ext_vector_type(8)));
typedef __bf16 bf16x4 __attribute__((ext_vector_type(4)));
typedef float  f32x4  __attribute__((ext_vector_type(4)));
typedef unsigned int u32;

#define E_DIM 1024
#define S_LEN 2048
#define BATCH 2
#define NH 16
#define DH 64

#define NEG_INF (-__builtin_inff())

union BU { u32 u[4]; bf16x8 h; };

__device__ __forceinline__ u32 cvtpk_bf16(float lo, float hi) {
    u32 r;
    asm("v_cvt_pk_bf16_f32 %0, %1, %2" : "=v"(r) : "v"(lo), "v"(hi));
    return r;
}
__device__ __forceinline__ void pswap32(u32 &a, u32 &b) {
    asm("v_permlane32_swap_b32 %0, %1" : "+v"(a), "+v"(b));
}
__device__ __forceinline__ void pswap16(u32 &a, u32 &b) {
    asm("v_permlane16_swap_b32 %0, %1" : "+v"(a), "+v"(b));
}
// raw v_exp_f32 (2^x); avoids ocml exp2f fixup code. exp(-inf)=0 as needed.
__device__ __forceinline__ float fast_exp2(float x) {
    float r;
    asm("v_exp_f32 %0, %1" : "=v"(r) : "v"(x));
    return r;
}

// async global->LDS, 16B per lane; LDS dst = wave-uniform base + lane*16 (m104)
__device__ __forceinline__ void load_lds16(const bf16* g, bf16* l) {
    __builtin_amdgcn_global_load_lds(
        (const __attribute__((address_space(1))) void*)g,
        (__attribute__((address_space(3))) void*)l, 16, 0, 0);
}

// ---------------------------------------------------------------------------
// fp32 -> bf16 conversion for x, Wq, Wk, Wv, Wo
// ---------------------------------------------------------------------------
__global__ __launch_bounds__(256) void convert_kernel(
    const float* __restrict__ s0, const float* __restrict__ s1,
    const float* __restrict__ s2, const float* __restrict__ s3,
    const float* __restrict__ s4,
    bf16* __restrict__ d0, bf16* __restrict__ d1, bf16* __restrict__ d2,
    bf16* __restrict__ d3, bf16* __restrict__ d4,
    int n0, int n1)
{
    const float* src; bf16* dst; int n;
    switch (blockIdx.y) {
        case 0:  src = s0; dst = d0; n = n0; break;
        case 1:  src = s1; dst = d1; n = n1; break;
        case 2:  src = s2; dst = d2; n = n1; break;
        case 3:  src = s3; dst = d3; n = n1; break;
        default: src = s4; dst = d4; n = n1; break;
    }
    int i = (blockIdx.x * 256 + threadIdx.x) * 4;
    if (i >= n) return;
    float4 v = *(const float4*)(src + i);
    bf16x4 o;
    o[0] = (bf16)v.x; o[1] = (bf16)v.y; o[2] = (bf16)v.z; o[3] = (bf16)v.w;
    *(bf16x4*)(dst + i) = o;
}

// ---------------------------------------------------------------------------
// QKV GEMM, R11: 256x256 tile, BK=64, 512 threads (8 waves, 2Mx4N), 2-buffer
// COUNTED-vmcnt pipeline (T3+T4): issue next K-tile's 8 global_load_lds
// BEFORE "s_waitcnt vmcnt(8)" + raw s_barrier -> staged loads stay in flight
// across the barrier (the m97 structure's __syncthreads drains vmcnt(0) every
// iter = the structural stall R6/R7/R10 could not remove). Buffer-reuse
// safety: per-wave lgkmcnt(0) + second barrier after compute, so buf[cur]'s
// ds_reads complete before any wave re-stages it next iteration.
// T2 swizzle (rule 21, both-sides involution on 16B slots): LDS[row][slot]
// holds global[row][slot ^ (row&7)] via pre-swizzled global source (LDS dest
// linear for global_load_lds); reads use slot = (ks*4+quad) ^ (l16&7).
// T5 setprio around the MFMA cluster. Grid 192 = 16m x 12n, XCD-chunked.
// ---------------------------------------------------------------------------
__global__ __launch_bounds__(512) void gemm256_kernel(
    const bf16* __restrict__ A,
    const bf16* __restrict__ W,
    const float* __restrict__ bias0, const float* __restrict__ bias1,
    const float* __restrict__ bias2,
    bf16* __restrict__ outQ, bf16* __restrict__ outK, bf16* __restrict__ outVt)
{
    __shared__ bf16 As[2][256 * 64];   // 64 KB
    __shared__ bf16 Bs[2][256 * 64];   // 64 KB  (128 KB total -> 1 block/CU)

    const int bid = blockIdx.x;
    const int xcd = bid & 7, idx = bid >> 3;      // idx 0..23
    const int mtile = (xcd >> 1) * 4 + idx / 6;   // 16 m-tiles
    const int ntile = (xcd & 1) * 6 + idx % 6;    // 12 n-tiles
    const int bm = mtile * 256, bn = ntile * 256;
    const int mode = bn >> 10;                    // tile lies in one mode (256|1024)
    const float* bias = (mode == 1) ? bias1 : (mode == 2 ? bias2 : bias0);

    const int t = threadIdx.x;
    const int lane = t & 63, w = t >> 6;
    const int quad = lane >> 4, l16 = lane & 15;
    const int wrow = (w & 1) * 128, wcol = (w >> 1) * 64;

    // staging: wave w, chunk c stages rows [c*64 + w*8, +8), lane covers slot
    // (lane&7) at row +lane>>3. Global slot pre-swizzled: ^ (row&7).
    const int grow  = w * 8 + (lane >> 3);                 // + c*64
    const int gslot = (lane & 7) ^ ((lane >> 3) & 7);      // row&7 == (lane>>3)&7
    const bf16* Ag = A + (size_t)(bm + grow) * E_DIM + gslot * 8;
    const bf16* Wg = W + (size_t)(bn + grow) * E_DIM + gslot * 8;

#define STAGE256(buf, kt) do {                                              \
    const bf16* ag_ = Ag + (kt) * 64;                                       \
    const bf16* wg_ = Wg + (kt) * 64;                                       \
    bf16* la_ = As[buf] + w * 512;                                          \
    bf16* lb_ = Bs[buf] + w * 512;                                          \
    load_lds16(ag_,                 la_);                                   \
    load_lds16(ag_ +  64 * E_DIM,   la_ + 4096);                            \
    load_lds16(ag_ + 128 * E_DIM,   la_ + 8192);                            \
    load_lds16(ag_ + 192 * E_DIM,   la_ + 12288);                           \
    load_lds16(wg_,                 lb_);                                   \
    load_lds16(wg_ +  64 * E_DIM,   lb_ + 4096);                            \
    load_lds16(wg_ + 128 * E_DIM,   lb_ + 8192);                            \
    load_lds16(wg_ + 192 * E_DIM,   lb_ + 12288);                           \
} while (0)

    f32x4 acc[8][4];
#pragma unroll
    for (int m = 0; m < 8; m++)
#pragma unroll
        for (int j = 0; j < 4; j++) acc[m][j] = f32x4{0.f, 0.f, 0.f, 0.f};

    STAGE256(0, 0);

    int cur = 0;
    for (int i = 0; i < 16; i++) {          // K = 16 x 64
        if (i < 15) {
            STAGE256(cur ^ 1, i + 1);       // issue BEFORE the wait (T14/T4)
            asm volatile("s_waitcnt vmcnt(8)" ::: "memory");   // tile i landed; 8 in flight
        } else {
            asm volatile("s_waitcnt vmcnt(0)" ::: "memory");
        }
        __builtin_amdgcn_s_barrier();       // raw barrier: no vmcnt(0) drain

        __builtin_amdgcn_s_setprio(1);
#pragma unroll
        for (int ks = 0; ks < 2; ks++) {
            bf16x8 bfr[4];
#pragma unroll
            for (int j = 0; j < 4; j++)
                bfr[j] = *(const bf16x8*)(Bs[cur] + (wcol + j * 16 + l16) * 64
                                          + (((ks * 4 + quad) ^ (l16 & 7)) * 8));
#pragma unroll
            for (int m = 0; m < 8; m++) {
                bf16x8 af = *(const bf16x8*)(As[cur] + (wrow + m * 16 + l16) * 64
                                             + (((ks * 4 + quad) ^ (l16 & 7)) * 8));
#pragma unroll
                for (int j = 0; j < 4; j++)
                    acc[m][j] = __builtin_amdgcn_mfma_f32_16x16x32_bf16(af, bfr[j], acc[m][j], 0, 0, 0);
            }
        }
        __builtin_amdgcn_s_setprio(0);

        asm volatile("s_waitcnt lgkmcnt(0)" ::: "memory");  // my ds_reads done
        __builtin_amdgcn_s_barrier();       // all reads done -> buf reusable
        cur ^= 1;
    }
#undef STAGE256

    // epilogue: identical store convention to the verified 128-tile kernel
#pragma unroll
    for (int j = 0; j < 4; j++) {
        const int n = bn + wcol + j * 16 + l16;   // absolute col (0..3071)
        const int nl = n & 1023;
        const float bv = bias[nl];
#pragma unroll
        for (int m = 0; m < 8; m++) {
            const int m0 = bm + wrow + m * 16 + quad * 4;
            if (mode == 2) {
                const int b_ = m0 >> 11, s0 = m0 & (S_LEN - 1);
                const int h = nl >> 6, d = nl & 63;
                bf16x4 pv;
#pragma unroll
                for (int r = 0; r < 4; r++) pv[r] = (bf16)(acc[m][j][r] + bv);
                *(bf16x4*)(outVt + ((size_t)((b_ * NH + h) * DH + d)) * S_LEN + s0) = pv;
            } else {
                bf16* o = (mode == 0) ? outQ : outK;
                // Q pre-scaled by 0.125 * log2(e) so attn softmax uses exp2
                const float sc = (mode == 0) ? 0.18033688f : 1.0f;
                const int h = nl >> 6, d = nl & 63;
#pragma unroll
                for (int r = 0; r < 4; r++) {
                    const int mm = m0 + r;
                    const int b_ = mm >> 11, s = mm & (S_LEN - 1);
                    o[((size_t)(b_ * NH + h) * S_LEN + s) * DH + d] = (bf16)((acc[m][j][r] + bv) * sc);
                }
            }
        }
    }
}

// ---------------------------------------------------------------------------
// GEMM (out-projection only): verified m97 structure + R8 XOR-swizzle.
// ---------------------------------------------------------------------------
__global__ __launch_bounds__(256) void gemm_kernel(
    const bf16* __restrict__ A,
    const bf16* __restrict__ W,
    const float* __restrict__ bias0,
    float* __restrict__ outF)
{
    __shared__ bf16 As[2][128 * 32];
    __shared__ bf16 Bs[2][128 * 32];

    const int bid = blockIdx.x;
    const int xcd = bid & 7, idx = bid >> 3;
    const int mtile = (xcd >> 1) * 8 + (idx >> 2);
    const int ntile = (xcd & 1) * 4 + (idx & 3);
    const int bm = mtile * 128, bn = ntile * 128;
    const float* bias = bias0;

    const int t = threadIdx.x;
    const int lane = t & 63, w = t >> 6;
    const int quad = lane >> 4, l16 = lane & 15;
    const int wm = (w & 1) * 64, wn = (w >> 1) * 64;

    const int r0 = w * 16;
    const int srow = r0 + (lane >> 2);
    const int scol = ((lane & 3) ^ ((lane >> 3) & 3)) * 8;
    const bf16* Ag0 = A + (size_t)(bm + srow) * E_DIM + scol;
    const bf16* Ag1 = Ag0 + (size_t)64 * E_DIM;
    const bf16* Wg0 = W + (size_t)(bn + srow) * E_DIM + scol;
    const bf16* Wg1 = Wg0 + (size_t)64 * E_DIM;

    f32x4 acc[4][4];
#pragma unroll
    for (int i = 0; i < 4; i++)
#pragma unroll
        for (int j = 0; j < 4; j++) acc[i][j] = f32x4{0.f, 0.f, 0.f, 0.f};

    load_lds16(Ag0, As[0] + r0 * 32);
    load_lds16(Ag1, As[0] + (64 + r0) * 32);
    load_lds16(Wg0, Bs[0] + r0 * 32);
    load_lds16(Wg1, Bs[0] + (64 + r0) * 32);

    const int rchunk = (quad ^ ((l16 >> 1) & 3)) * 8;

    int cur = 0;
    for (int kt = 0; kt < E_DIM; kt += 32) {
        __syncthreads();

        if (kt + 32 < E_DIM) {
            const int nxt = cur ^ 1;
            load_lds16(Ag0 + kt + 32, As[nxt] + r0 * 32);
            load_lds16(Ag1 + kt + 32, As[nxt] + (64 + r0) * 32);
            load_lds16(Wg0 + kt + 32, Bs[nxt] + r0 * 32);
            load_lds16(Wg1 + kt + 32, Bs[nxt] + (64 + r0) * 32);
        }

        bf16x8 af[4], bfr[4];
#pragma unroll
        for (int i = 0; i < 4; i++)
            af[i] = *(const bf16x8*)(As[cur] + (wm + i * 16 + l16) * 32 + rchunk);
#pragma unroll
        for (int j = 0; j < 4; j++)
            bfr[j] = *(const bf16x8*)(Bs[cur] + (wn + j * 16 + l16) * 32 + rchunk);
#pragma unroll
        for (int i = 0; i < 4; i++)
#pragma unroll
            for (int j = 0; j < 4; j++)
                acc[i][j] = __builtin_amdgcn_mfma_f32_16x16x32_bf16(af[i], bfr[j], acc[i][j], 0, 0, 0);

        cur ^= 1;
    }

#pragma unroll
    for (int j = 0; j < 4; j++) {
        const int n = bn + wn + j * 16 + l16;
        const float bv = bias[n];
#pragma unroll
        for (int i = 0; i < 4; i++) {
            const int m0 = bm + wm + i * 16 + quad * 4;
#pragma unroll
            for (int r = 0; r < 4; r++)
                outF[(size_t)(m0 + r) * E_DIM + n] = acc[i][j][r] + bv;
        }
    }
}

// ---------------------------------------------------------------------------
// Flash attention, causal — balanced chunks with NON-ATOMIC partial stores.
// (R3/R6 structure, verified; unchanged)
// ---------------------------------------------------------------------------
__global__ __launch_bounds__(512, 4) void attn_kernel(
    const bf16* __restrict__ Qb, const bf16* __restrict__ Kb,
    const bf16* __restrict__ Vtb,
    float* __restrict__ Opart, float* __restrict__ Lpart)
{
    __shared__ __align__(16) char smem[35840];
    bf16* Ks = (bf16*)smem;              // [128][72]  18.0 KB
    bf16* Vs = (bf16*)(smem + 18432);    // [64][136]  17.0 KB

    const int t = threadIdx.x, lane = t & 63, w = t >> 6;
    const int quad = lane >> 4, l16 = lane & 15;
    const int qs = w & 3, kh = w >> 2;   // q-stripe 0..3, k-half 0..1

    // block -> (xcd, bh, chunk): i = [g(0..39)][bh_local(0..3)][xcd(0..7)]
    const int i = blockIdx.x;
    const int xcd = i & 7, idx = i >> 3;       // idx 0..159
    const int bh  = (xcd << 2) | (idx & 3);    // 4 bh per XCD (L2-resident K/V)
    const int g   = idx >> 2;                  // chunk id 0..39
    int qt, c0;
    if (g < 4)       { qt = g;                            c0 = 0; }
    else if (g < 12) { int u = g - 4;  qt = 4 + (u >> 1); c0 = u & 1; }
    else if (g < 24) { int u = g - 12; qt = 8 + u / 3;    c0 = u % 3; }
    else             { int u = g - 24; qt = 12 + (u >> 2); c0 = u & 3; }
    const int k0 = c0 * 4;                          // first k-tile of chunk
    const int k1 = (k0 + 3 < qt) ? k0 + 3 : qt;     // last k-tile (incl)

    const bf16* Qg = Qb + (size_t)bh * S_LEN * DH;
    const bf16* Kg = Kb + (size_t)bh * S_LEN * DH;
    const bf16* Vg = Vtb + (size_t)bh * DH * S_LEN;
    float* Op = Opart + ((size_t)(bh * 16 + qt) * 4 + c0) * (128 * 64);
    float* Lp = Lpart + ((size_t)(bh * 16 + qt) * 4 + c0) * 128;

    const int qrow0 = qt * 128 + qs * 32;

    // Q B-fragments: lane = q-row (l16) of each 16-q stripe, cols d
    bf16x8 qf[2][2];
#pragma unroll
    for (int qh = 0; qh < 2; qh++) {
        const bf16* qp = Qg + (size_t)(qrow0 + qh * 16 + l16) * DH + quad * 8;
        qf[qh][0] = *(const bf16x8*)(qp);
        qf[qh][1] = *(const bf16x8*)(qp + 32);
    }

    f32x4 o[2][4];          // O^T frags: lane=q(l16), regs d=dt*16+quad*4+r
    f32x4 lacc[2];          // partial row sums (this lane's k subset)
#pragma unroll
    for (int qh = 0; qh < 2; qh++) {
        lacc[qh] = f32x4{0.f, 0.f, 0.f, 0.f};
#pragma unroll
        for (int dt = 0; dt < 4; dt++) o[qh][dt] = f32x4{0.f, 0.f, 0.f, 0.f};
    }

    const int kr0 = t >> 3, kce = (t & 7) * 8;      // K staging map
    const int vr0 = t >> 4, vce = (t & 15) * 8;     // V staging map

    // prologue staging load (first tile of chunk)
    const int kb0 = k0 * 128;
    uint4 kA = *(const uint4*)(Kg + (size_t)(kb0 + kr0) * DH + kce);
    uint4 kB = *(const uint4*)(Kg + (size_t)(kb0 + kr0 + 64) * DH + kce);
    uint4 vA = *(const uint4*)(Vg + (size_t)vr0 * S_LEN + kb0 + vce);
    uint4 vB = *(const uint4*)(Vg + (size_t)(vr0 + 32) * S_LEN + kb0 + vce);

    for (int kt = k0; kt <= k1; kt++) {
        __syncthreads();            // previous tile's LDS reads done
        *(uint4*)(Ks + kr0 * 72 + kce) = kA;
        *(uint4*)(Ks + (kr0 + 64) * 72 + kce) = kB;
        *(uint4*)(Vs + vr0 * 136 + vce) = vA;
        *(uint4*)(Vs + (vr0 + 32) * 136 + vce) = vB;
        __syncthreads();            // staged tile visible

        if (kt < k1) {              // T14: issue next tile's loads under compute
            const int kb = (kt + 1) * 128;
            kA = *(const uint4*)(Kg + (size_t)(kb + kr0) * DH + kce);
            kB = *(const uint4*)(Kg + (size_t)(kb + kr0 + 64) * DH + kce);
            vA = *(const uint4*)(Vg + (size_t)vr0 * S_LEN + kb + vce);
            vB = *(const uint4*)(Vg + (size_t)(vr0 + 32) * S_LEN + kb + vce);
        }

        const bool diag = (kt == qt);

#pragma unroll
        for (int itp = 0; itp < 2; itp++) {
            // ---- S^T = mfma(K, Q): lane holds S[q=l16][k=itg*16+quad*4+r]
            f32x4 p[2][2];
#pragma unroll
            for (int e = 0; e < 2; e++) {
                const int itg = kh * 4 + itp * 2 + e;
                const bf16* kp = Ks + (itg * 16 + l16) * 72 + quad * 8;
                bf16x8 kf0 = *(const bf16x8*)(kp);
                bf16x8 kf1 = *(const bf16x8*)(kp + 32);
#pragma unroll
                for (int qh = 0; qh < 2; qh++) {
                    f32x4 s = __builtin_amdgcn_mfma_f32_16x16x32_bf16(
                        kf0, qf[qh][0], f32x4{0.f, 0.f, 0.f, 0.f}, 0, 0, 0);
                    s = __builtin_amdgcn_mfma_f32_16x16x32_bf16(
                        kf1, qf[qh][1], s, 0, 0, 0);
                    if (diag) {
                        const int kloc = kh * 64 + (itp * 2 + e) * 16 + quad * 4;
                        const int qloc = qs * 32 + qh * 16 + l16;
#pragma unroll
                        for (int r = 0; r < 4; r++)
                            if (kloc + r > qloc) s[r] = NEG_INF;
                    }
                    f32x4 pe;
#pragma unroll
                    for (int r = 0; r < 4; r++) pe[r] = fast_exp2(s[r]);
                    lacc[qh] += pe;
                    p[qh][e] = pe;
                }
            }

            // ---- P -> B-frag: cvt_pk pairs, then swap32+swap16 places
            // k = quad*8 + {0..7} at each quad (in-register transpose)
            BU bu0, bu1;
            {
                u32 a0 = cvtpk_bf16(p[0][0][0], p[0][0][1]);
                u32 a1 = cvtpk_bf16(p[0][0][2], p[0][0][3]);
                u32 b0 = cvtpk_bf16(p[0][1][0], p[0][1][1]);
                u32 b1 = cvtpk_bf16(p[0][1][2], p[0][1][3]);
                pswap32(a0, b0); pswap16(a0, b0);
                pswap32(a1, b1); pswap16(a1, b1);
                bu0.u[0] = a0; bu0.u[1] = a1; bu0.u[2] = b0; bu0.u[3] = b1;
            }
            {
                u32 a0 = cvtpk_bf16(p[1][0][0], p[1][0][1]);
                u32 a1 = cvtpk_bf16(p[1][0][2], p[1][0][3]);
                u32 b0 = cvtpk_bf16(p[1][1][0], p[1][1][1]);
                u32 b1 = cvtpk_bf16(p[1][1][2], p[1][1][3]);
                pswap32(a0, b0); pswap16(a0, b0);
                pswap32(a1, b1); pswap16(a1, b1);
                bu1.u[0] = a0; bu1.u[1] = a1; bu1.u[2] = b0; bu1.u[3] = b1;
            }

            // ---- O^T += mfma(V^T-frag, P-frag)
            const int ksg = kh * 2 + itp;
#pragma unroll
            for (int dt = 0; dt < 4; dt++) {
                bf16x8 vf = *(const bf16x8*)(Vs + (dt * 16 + l16) * 136 + ksg * 32 + quad * 8);
                o[0][dt] = __builtin_amdgcn_mfma_f32_16x16x32_bf16(vf, bu0.h, o[0][dt], 0, 0, 0);
                o[1][dt] = __builtin_amdgcn_mfma_f32_16x16x32_bf16(vf, bu1.h, o[1][dt], 0, 0, 0);
            }
        }
    }

    // ---- epilogue: quad-reduce l, cross-k-half combine via LDS, then
    // coalesced f32x4 partial stores into this chunk's own slot.
    float lsum[2];
#pragma unroll
    for (int qh = 0; qh < 2; qh++) {
        float l = lacc[qh][0] + lacc[qh][1] + lacc[qh][2] + lacc[qh][3];
        l += __shfl_xor(l, 16);
        l += __shfl_xor(l, 32);
        lsum[qh] = l;
    }

    __syncthreads();                         // all LDS reads done; reuse smem
    f32x4* Or = (f32x4*)smem;                // 2048 x 16B = 32 KB
    float*  Lr = (float*)(smem + 32768);     // 128 x 4B

    if (kh == 1) {
#pragma unroll
        for (int qh = 0; qh < 2; qh++) {
#pragma unroll
            for (int dt = 0; dt < 4; dt++)
                Or[(((qs * 2 + qh) * 4 + dt) * 4 + quad) * 16 + l16] = o[qh][dt];
            if (quad == 0) Lr[(qs * 2 + qh) * 16 + l16] = lsum[qh];
        }
    }
    __syncthreads();
    if (kh == 0) {
#pragma unroll
        for (int qh = 0; qh < 2; qh++) {
            const float lc = lsum[qh] + Lr[(qs * 2 + qh) * 16 + l16];
            const int row = qs * 32 + qh * 16 + l16;
            if (quad == 0) Lp[row] = lc;
#pragma unroll
            for (int dt = 0; dt < 4; dt++) {
                f32x4 ov = o[qh][dt] + Or[(((qs * 2 + qh) * 4 + dt) * 4 + quad) * 16 + l16];
                *(f32x4*)(Op + (size_t)row * 64 + dt * 16 + quad * 4) = ov;
            }
        }
    }
}

// ---------------------------------------------------------------------------
// normalize: sum the live partial slots, divide, write bf16 Ab[b][s][h*64+d]
// ---------------------------------------------------------------------------
__global__ __launch_bounds__(256) void norm_kernel(
    const float* __restrict__ Opart, const float* __restrict__ Lpart,
    bf16* __restrict__ Ab)
{
    const int j = (blockIdx.x * 256 + threadIdx.x) * 4;   // 4,194,304 total
    const int b = j >> 21, s = (j >> 10) & (S_LEN - 1), e = j & 1023;
    const int h = e >> 6, d = e & 63;
    const int bh = b * NH + h;
    const int qt = s >> 7, row = s & 127;
    const int nc = (qt >> 2) + 1;                 // live slots for this q-tile
    const float* Op = Opart + ((size_t)(bh * 16 + qt) * 4) * (128 * 64)
                    + (size_t)row * 64 + d;
    const float* Lp = Lpart + ((size_t)(bh * 16 + qt) * 4) * 128 + row;
    f32x4 ov = *(const f32x4*)Op;
    float l = Lp[0];
    for (int c = 1; c < nc; c++) {
        ov += *(const f32x4*)(Op + c * (128 * 64));
        l += Lp[c * 128];
    }
    const float inv = 1.0f / l;
    bf16x4 w4;
#pragma unroll
    for (int r = 0; r < 4; r++) w4[r] = (bf16)(ov[r] * inv);
    *(bf16x4*)(Ab + j) = w4;
}

// ---------------------------------------------------------------------------
extern "C" void kernel_launch(void* const* d_in, const int* in_sizes, int n_in,
                              void* d_out, int out_size, void* d_ws, size_t ws_size,
                              hipStream_t stream)
{
    const float* x  = (const float*)d_in[0];
    const float* Wq = (const float*)d_in[1];
    const float* bq = (const float*)d_in[2];
    const float* Wk = (const float*)d_in[3];
    const float* bk = (const float*)d_in[4];
    const float* Wv = (const float*)d_in[5];
    const float* bv = (const float*)d_in[6];
    const float* Wo = (const float*)d_in[7];
    const float* bo = (const float*)d_in[8];
    float* out = (float*)d_out;

    char* ws = (char*)d_ws;
    const size_t MB = 1ull << 20;
    bf16*  xb    = (bf16*)(ws + 0);        //  8 MB: x bf16 [4096][1024]
    bf16*  wqb   = (bf16*)(ws + 8 * MB);   //  2 MB (wqb/wkb/wvb contiguous = [3072][1024])
    bf16*  wkb   = (bf16*)(ws + 10 * MB);  //  2 MB
    bf16*  wvb   = (bf16*)(ws + 12 * MB);  //  2 MB
    bf16*  wob   = (bf16*)(ws + 14 * MB);  //  2 MB
    bf16*  Qb    = (bf16*)(ws + 16 * MB);  //  8 MB: [b][h][s][d] (scaled 0.125*log2e)
    bf16*  Kb    = (bf16*)(ws + 24 * MB);  //  8 MB: [b][h][s][d]
    bf16*  Vtb   = (bf16*)(ws + 32 * MB);  //  8 MB: [b][h][d][s]
    bf16*  Ab    = (bf16*)(ws + 40 * MB);  //  8 MB: attn out [b][s][e]
    float* Opart = (float*)(ws + 48 * MB); // 64 MB: f32 [bh][qt][4][128][64]
    float* Lpart = (float*)(ws + 112 * MB);//  1 MB: f32 [bh][qt][4][128]

    // 1) fp32 -> bf16 for x and the four weight matrices
    convert_kernel<<<dim3(4096, 5), 256, 0, stream>>>(
        x, Wq, Wk, Wv, Wo, xb, wqb, wkb, wvb, wob, 4194304, 1048576);

    // 2) fused Q/K/V projection: 192 x (256x256) counted-vmcnt pipeline
    gemm256_kernel<<<dim3(192), 512, 0, stream>>>(
        xb, wqb, bq, bk, bv, Qb, Kb, Vtb);

    // 3) causal flash attention, balanced chunks -> per-chunk partial slots
    attn_kernel<<<dim3(1280), 512, 0, stream>>>(Qb, Kb, Vtb, Opart, Lpart);

    // 4) reduce partial slots + normalize -> bf16 Ab
    norm_kernel<<<dim3(4096), 256, 0, stream>>>(Opart, Lpart, Ab);

    // 5) output projection -> fp32 d_out (verified m97 structure)
    gemm_kernel<<<dim3(256), 256, 0, stream>>>(Ab, wob, bo, out);
}